// Round 1
// baseline (150.541 us; speedup 1.0000x reference)
//
#include <hip/hip_runtime.h>

typedef __bf16 bf16x8 __attribute__((ext_vector_type(8)));
typedef float f32x16 __attribute__((ext_vector_type(16)));

constexpr int S = 128, R = 256, CM = 256, C = 32, CZ = 128;

__device__ __forceinline__ unsigned short f32_to_bf16(float f) {
    unsigned int u = __builtin_bit_cast(unsigned int, f);
    u += 0x7FFFu + ((u >> 16) & 1u);
    return (unsigned short)(u >> 16);
}

// K0: WT2[cz][e*32 + c] = bf16( W[(c*32 + e)*128 + cz] )
__global__ __launch_bounds__(256) void k_wt(const float* __restrict__ W,
                                            unsigned short* __restrict__ WT2) {
    int t = threadIdx.x;
    int ce = blockIdx.x * 2 + (t >> 7);   // 0..1023 (grid 512)
    int cz = t & 127;
    float v = W[(size_t)ce * 128 + cz];   // coalesced over cz
    int c = ce >> 5, e = ce & 31;
    WT2[(size_t)cz * 1024 + e * 32 + c] = f32_to_bf16(v);
}

// K1: aT[r][c][s] = bf16( sum_m msa[s][r][m] * left[m][c] ), bT likewise with right.
// f32 VALU; msa rows staged in padded LDS.
__global__ __launch_bounds__(256) void k_proj(const float* __restrict__ msa,
                                              const float* __restrict__ left,
                                              const float* __restrict__ right,
                                              unsigned short* __restrict__ aT,
                                              unsigned short* __restrict__ bT) {
    __shared__ float lds[32 * 260];       // 32 s-rows x 256 m (+pad to 260)
    const int r = blockIdx.x;
    const int s0 = blockIdx.y * 32;
    const int t = threadIdx.x;

    // stage msa[s0+row][r][0..255], coalesced float4
#pragma unroll
    for (int it = 0; it < 8; ++it) {
        int idx = it * 256 + t;
        int row = idx >> 6;
        int c4 = (idx & 63) << 2;
        float4 v = *(const float4*)&msa[((size_t)(s0 + row) * R + r) * CM + c4];
        *(float4*)&lds[row * 260 + c4] = v;
    }
    __syncthreads();

    const int c = t & 31;
    const int sj = t >> 5;                // 0..7, owns s rows sj*4..sj*4+3
    float accA[4] = {0.f, 0.f, 0.f, 0.f};
    float accB[4] = {0.f, 0.f, 0.f, 0.f};

    for (int m4 = 0; m4 < 64; ++m4) {
        int m = m4 << 2;
        float l0 = left[(m + 0) * 32 + c], l1 = left[(m + 1) * 32 + c];
        float l2 = left[(m + 2) * 32 + c], l3 = left[(m + 3) * 32 + c];
        float r0 = right[(m + 0) * 32 + c], r1 = right[(m + 1) * 32 + c];
        float r2 = right[(m + 2) * 32 + c], r3 = right[(m + 3) * 32 + c];
#pragma unroll
        for (int k = 0; k < 4; ++k) {
            float4 v = *(const float4*)&lds[(sj * 4 + k) * 260 + m];
            accA[k] = fmaf(v.x, l0, accA[k]);
            accA[k] = fmaf(v.y, l1, accA[k]);
            accA[k] = fmaf(v.z, l2, accA[k]);
            accA[k] = fmaf(v.w, l3, accA[k]);
            accB[k] = fmaf(v.x, r0, accB[k]);
            accB[k] = fmaf(v.y, r1, accB[k]);
            accB[k] = fmaf(v.z, r2, accB[k]);
            accB[k] = fmaf(v.w, r3, accB[k]);
        }
    }

    const int sbase = s0 + sj * 4;
    ushort4 ha, hb;
    ha.x = f32_to_bf16(accA[0]); ha.y = f32_to_bf16(accA[1]);
    ha.z = f32_to_bf16(accA[2]); ha.w = f32_to_bf16(accA[3]);
    hb.x = f32_to_bf16(accB[0]); hb.y = f32_to_bf16(accB[1]);
    hb.z = f32_to_bf16(accB[2]); hb.w = f32_to_bf16(accB[3]);
    *(ushort4*)&aT[(size_t)(r * 32 + c) * 128 + sbase] = ha;
    *(ushort4*)&bT[(size_t)(r * 32 + c) * 128 + sbase] = hb;
}

// K2: per workgroup (4 waves): pair tile of 8 r x 4 t = 32 pairs.
// Phase A: G[p][c][e] = sum_s a[r,s,c] b[t,s,e]  (mfma 32x32x16 bf16, K=128)
// -> LDS (bf16, swizzled). Phase B: out[p][cz] = sum_ce G * W (mfma, K=1024).
__global__ __launch_bounds__(256) void k_main(const unsigned short* __restrict__ aT,
                                              const unsigned short* __restrict__ bT,
                                              const unsigned short* __restrict__ WT2,
                                              float* __restrict__ out) {
    __shared__ __align__(16) unsigned short Gs[32 * 1024];  // 64 KB

    const int t = threadIdx.x;
    const int w = t >> 6;           // wave 0..3
    const int l = t & 63;
    const int lane = l & 31;
    const int kh = l >> 5;          // k-half select for A/B fragments
    const int r0 = blockIdx.x * 8;
    const int t0 = blockIdx.y * 4;

    // ---------------- Phase A ----------------
    f32x16 acc[2][4];
#pragma unroll
    for (int i = 0; i < 2; ++i)
#pragma unroll
        for (int j = 0; j < 4; ++j)
#pragma unroll
            for (int q = 0; q < 16; ++q) acc[i][j][q] = 0.f;

    const bf16x8* ab[2];
    const bf16x8* bb[4];
#pragma unroll
    for (int i = 0; i < 2; ++i)
        ab[i] = (const bf16x8*)&aT[((size_t)(r0 + 2 * w + i) * 32 + lane) * 128 + 8 * kh];
#pragma unroll
    for (int j = 0; j < 4; ++j)
        bb[j] = (const bf16x8*)&bT[((size_t)(t0 + j) * 32 + lane) * 128 + 8 * kh];

#pragma unroll
    for (int ks = 0; ks < 8; ++ks) {
        bf16x8 af0 = ab[0][2 * ks];
        bf16x8 af1 = ab[1][2 * ks];
        bf16x8 bf0 = bb[0][2 * ks];
        bf16x8 bf1 = bb[1][2 * ks];
        bf16x8 bf2 = bb[2][2 * ks];
        bf16x8 bf3 = bb[3][2 * ks];
        acc[0][0] = __builtin_amdgcn_mfma_f32_32x32x16_bf16(af0, bf0, acc[0][0], 0, 0, 0);
        acc[0][1] = __builtin_amdgcn_mfma_f32_32x32x16_bf16(af0, bf1, acc[0][1], 0, 0, 0);
        acc[0][2] = __builtin_amdgcn_mfma_f32_32x32x16_bf16(af0, bf2, acc[0][2], 0, 0, 0);
        acc[0][3] = __builtin_amdgcn_mfma_f32_32x32x16_bf16(af0, bf3, acc[0][3], 0, 0, 0);
        acc[1][0] = __builtin_amdgcn_mfma_f32_32x32x16_bf16(af1, bf0, acc[1][0], 0, 0, 0);
        acc[1][1] = __builtin_amdgcn_mfma_f32_32x32x16_bf16(af1, bf1, acc[1][1], 0, 0, 0);
        acc[1][2] = __builtin_amdgcn_mfma_f32_32x32x16_bf16(af1, bf2, acc[1][2], 0, 0, 0);
        acc[1][3] = __builtin_amdgcn_mfma_f32_32x32x16_bf16(af1, bf3, acc[1][3], 0, 0, 0);
    }

    // Write G tiles to LDS as bf16, storage index ce' = e*32 + c (e = D-col = lane,
    // c = D-row). 4 consecutive rows (regs 4q..4q+3) pack into one 8B write.
    // Swizzle on 16B chunks: P(L,p) = L ^ ((L>>2)&7) ^ (p&7).
#pragma unroll
    for (int i = 0; i < 2; ++i) {
#pragma unroll
        for (int j = 0; j < 4; ++j) {
            int p = (2 * w + i) * 4 + j;
            unsigned prow = (unsigned)p * 2048;
            int px = p & 7;
#pragma unroll
            for (int q = 0; q < 4; ++q) {
                int L = lane * 4 + q;              // (L>>2)&7 == lane&7
                int P = L ^ (lane & 7) ^ px;
                ushort4 hv;
                hv.x = f32_to_bf16(acc[i][j][4 * q + 0]);
                hv.y = f32_to_bf16(acc[i][j][4 * q + 1]);
                hv.z = f32_to_bf16(acc[i][j][4 * q + 2]);
                hv.w = f32_to_bf16(acc[i][j][4 * q + 3]);
                *(ushort4*)((char*)Gs + prow + P * 16 + kh * 8) = hv;
            }
        }
    }
    __syncthreads();

    // ---------------- Phase B ----------------
    // out[p][cz] = sum_{ce'} G[p][ce'] * WT2[cz][ce'],  M=32 pairs, N=32 cz per wave, K=1024
    f32x16 o;
#pragma unroll
    for (int q = 0; q < 16; ++q) o[q] = 0.f;

    const int czl = w * 32 + lane;
    const bf16x8* wb = (const bf16x8*)&WT2[(size_t)czl * 1024 + 8 * kh];
    const unsigned prow = (unsigned)lane * 2048;
    const int p7 = lane & 7;

#pragma unroll
    for (int kk = 0; kk < 64; ++kk) {
        int Lr = kk * 2 + kh;
        int P = Lr ^ ((Lr >> 2) & 7) ^ p7;
        bf16x8 gf = *(const bf16x8*)((const char*)Gs + prow + P * 16);
        bf16x8 wf = wb[2 * kk];
        o = __builtin_amdgcn_mfma_f32_32x32x16_bf16(gf, wf, o, 0, 0, 0);
    }

    // D[row=pair][col=cz-local]; row = (reg&3) + 8*(reg>>2) + 4*kh
#pragma unroll
    for (int reg = 0; reg < 16; ++reg) {
        int p = (reg & 3) + 8 * (reg >> 2) + 4 * kh;
        int pr = p >> 2, pt = p & 3;
        out[((size_t)(r0 + pr) * 256 + (t0 + pt)) * 128 + czl] = o[reg];
    }
}

extern "C" void kernel_launch(void* const* d_in, const int* in_sizes, int n_in,
                              void* d_out, int out_size, void* d_ws, size_t ws_size,
                              hipStream_t stream) {
    const float* msa = (const float*)d_in[0];
    const float* left = (const float*)d_in[1];
    const float* right = (const float*)d_in[2];
    const float* W = (const float*)d_in[3];

    unsigned short* aT = (unsigned short*)d_ws;              // [256][32][128] bf16 = 2 MB
    unsigned short* bT = aT + (size_t)R * 32 * 128;          // 2 MB
    unsigned short* WT2 = bT + (size_t)R * 32 * 128;         // [128][1024] bf16 = 256 KB
    float* outp = (float*)d_out;

    k_wt<<<512, 256, 0, stream>>>(W, WT2);
    k_proj<<<dim3(256, 4), 256, 0, stream>>>(msa, left, right, aT, bT);
    k_main<<<dim3(32, 64), 256, 0, stream>>>(aT, bT, WT2, outp);
}

// Round 2
// 128.824 us; speedup vs baseline: 1.1686x; 1.1686x over previous
//
#include <hip/hip_runtime.h>

typedef __bf16 bf16x8 __attribute__((ext_vector_type(8)));
typedef float f32x16 __attribute__((ext_vector_type(16)));

constexpr int S = 128, R = 256, CM = 256, C = 32, CZ = 128;

#define MFMA __builtin_amdgcn_mfma_f32_32x32x16_bf16

__device__ __forceinline__ unsigned short f32_to_bf16(float f) {
    unsigned int u = __builtin_bit_cast(unsigned int, f);
    u += 0x7FFFu + ((u >> 16) & 1u);
    return (unsigned short)(u >> 16);
}

// K0a: WT2[cz][e*32 + c] = bf16( W[(c*32 + e)*128 + cz] )
__global__ __launch_bounds__(256) void k_wt(const float* __restrict__ W,
                                            unsigned short* __restrict__ WT2) {
    int t = threadIdx.x;
    int ce = blockIdx.x * 2 + (t >> 7);
    int cz = t & 127;
    float v = W[(size_t)ce * 128 + cz];
    int c = ce >> 5, e = ce & 31;
    WT2[(size_t)cz * 1024 + e * 32 + c] = f32_to_bf16(v);
}

// K0b: WLRT[c][m], c in [0,64): c<32 -> left[m][c], else right[m][c-32]
__global__ __launch_bounds__(256) void k_wlr(const float* __restrict__ Lp,
                                             const float* __restrict__ Rp,
                                             unsigned short* __restrict__ WLRT) {
    int c = blockIdx.x;            // 0..63
    int m = threadIdx.x;           // 0..255
    const float* src = (c < 32) ? Lp : Rp;
    WLRT[(size_t)c * 256 + m] = f32_to_bf16(src[(size_t)m * 32 + (c & 31)]);
}

// K1 (MFMA): per block, one r. D[s][c] = sum_m msa[s][r][m] * WLR[m][c], c=0..63 (left|right).
// Output written directly as aT[r][c][s], bT[r][c][s] (bf16).
__global__ __launch_bounds__(256) void k_proj(const float* __restrict__ msa,
                                              const unsigned short* __restrict__ WLRT,
                                              unsigned short* __restrict__ aT,
                                              unsigned short* __restrict__ bT) {
    __shared__ __align__(16) unsigned short As[128 * 256];   // 64 KB, swizzled
    const int r = blockIdx.x;
    const int t = threadIdx.x;
    const int w = t >> 6;
    const int lane = t & 63;

    // stage msa[s][r][:] -> bf16 LDS, swizzle P = chunk ^ (row&15)
#pragma unroll 4
    for (int it = 0; it < 32; ++it) {
        int row = it * 4 + w;
        float4 v = *(const float4*)&msa[((size_t)row * R + r) * CM + lane * 4];
        ushort4 h;
        h.x = f32_to_bf16(v.x); h.y = f32_to_bf16(v.y);
        h.z = f32_to_bf16(v.z); h.w = f32_to_bf16(v.w);
        int P = (lane >> 1) ^ (row & 15);
        *(ushort4*)((char*)As + row * 512 + P * 16 + (lane & 1) * 8) = h;
    }
    __syncthreads();

    const int l31 = t & 31;
    const int kh = (t >> 5) & 1;
    f32x16 accL, accR;
#pragma unroll
    for (int q = 0; q < 16; ++q) { accL[q] = 0.f; accR[q] = 0.f; }

    const bf16x8* wbL = (const bf16x8*)&WLRT[(size_t)l31 * 256 + 8 * kh];
    const bf16x8* wbR = (const bf16x8*)&WLRT[(size_t)(32 + l31) * 256 + 8 * kh];
    const int srow = w * 32 + l31;
    const char* arow = (const char*)As + srow * 512;

#pragma unroll
    for (int ks = 0; ks < 16; ++ks) {
        int P = (2 * ks + kh) ^ (srow & 15);
        bf16x8 af = *(const bf16x8*)(arow + P * 16);
        accL = MFMA(af, wbL[2 * ks], accL, 0, 0, 0);
        accR = MFMA(af, wbR[2 * ks], accR, 0, 0, 0);
    }

    // D: col = l31 (c), row m -> s = w*32 + (reg&3) + 8*(reg>>2) + 4*kh
#pragma unroll
    for (int q = 0; q < 4; ++q) {
        int s0 = w * 32 + 8 * q + 4 * kh;
        ushort4 ha, hb;
        ha.x = f32_to_bf16(accL[4 * q + 0]); ha.y = f32_to_bf16(accL[4 * q + 1]);
        ha.z = f32_to_bf16(accL[4 * q + 2]); ha.w = f32_to_bf16(accL[4 * q + 3]);
        hb.x = f32_to_bf16(accR[4 * q + 0]); hb.y = f32_to_bf16(accR[4 * q + 1]);
        hb.z = f32_to_bf16(accR[4 * q + 2]); hb.w = f32_to_bf16(accR[4 * q + 3]);
        *(ushort4*)&aT[((size_t)(r * 32 + l31)) * 128 + s0] = ha;
        *(ushort4*)&bT[((size_t)(r * 32 + l31)) * 128 + s0] = hb;
    }
}

// K2: 32 pairs (8r x 4t) per block, 4 waves. Phase A outer-product (K=128) ->
// LDS bf16 (swizzled) -> Phase B projection (K=1024), both software-pipelined.
__global__ __launch_bounds__(256, 2) void k_main(const unsigned short* __restrict__ aT,
                                                 const unsigned short* __restrict__ bT,
                                                 const unsigned short* __restrict__ WT2,
                                                 float* __restrict__ out) {
    __shared__ __align__(16) unsigned short Gs[32 * 1024];   // 64 KB

    const int t = threadIdx.x;
    const int w = t >> 6;
    const int l = t & 63;
    const int lane = l & 31;
    const int kh = l >> 5;
    const int r0 = blockIdx.x * 8;
    const int t0 = blockIdx.y * 4;

    // ---------------- Phase A ----------------
    f32x16 acc[2][4];
#pragma unroll
    for (int i = 0; i < 2; ++i)
#pragma unroll
        for (int j = 0; j < 4; ++j)
#pragma unroll
            for (int q = 0; q < 16; ++q) acc[i][j][q] = 0.f;

    const bf16x8* ab0 = (const bf16x8*)&aT[((size_t)(r0 + 2 * w + 0) * 32 + lane) * 128 + 8 * kh];
    const bf16x8* ab1 = (const bf16x8*)&aT[((size_t)(r0 + 2 * w + 1) * 32 + lane) * 128 + 8 * kh];
    const bf16x8* bb0 = (const bf16x8*)&bT[((size_t)(t0 + 0) * 32 + lane) * 128 + 8 * kh];
    const bf16x8* bb1 = (const bf16x8*)&bT[((size_t)(t0 + 1) * 32 + lane) * 128 + 8 * kh];
    const bf16x8* bb2 = (const bf16x8*)&bT[((size_t)(t0 + 2) * 32 + lane) * 128 + 8 * kh];
    const bf16x8* bb3 = (const bf16x8*)&bT[((size_t)(t0 + 3) * 32 + lane) * 128 + 8 * kh];

    bf16x8 A0[2], B0[4], A1[2], B1[4];
#define LDA(Aa, Bb, ks) do { \
    Aa[0] = ab0[2 * (ks)]; Aa[1] = ab1[2 * (ks)]; \
    Bb[0] = bb0[2 * (ks)]; Bb[1] = bb1[2 * (ks)]; \
    Bb[2] = bb2[2 * (ks)]; Bb[3] = bb3[2 * (ks)]; } while (0)
#define PH_A(Aa, Bb) do { \
    acc[0][0] = MFMA(Aa[0], Bb[0], acc[0][0], 0, 0, 0); \
    acc[0][1] = MFMA(Aa[0], Bb[1], acc[0][1], 0, 0, 0); \
    acc[0][2] = MFMA(Aa[0], Bb[2], acc[0][2], 0, 0, 0); \
    acc[0][3] = MFMA(Aa[0], Bb[3], acc[0][3], 0, 0, 0); \
    acc[1][0] = MFMA(Aa[1], Bb[0], acc[1][0], 0, 0, 0); \
    acc[1][1] = MFMA(Aa[1], Bb[1], acc[1][1], 0, 0, 0); \
    acc[1][2] = MFMA(Aa[1], Bb[2], acc[1][2], 0, 0, 0); \
    acc[1][3] = MFMA(Aa[1], Bb[3], acc[1][3], 0, 0, 0); } while (0)

    LDA(A0, B0, 0);
#pragma unroll
    for (int ks = 0; ks < 8; ks += 2) {
        LDA(A1, B1, ks + 1);
        PH_A(A0, B0);
        LDA(A0, B0, (ks + 2) & 7);
        PH_A(A1, B1);
    }

    // G -> LDS bf16, row p (2048 B), chunk swizzle P = L ^ (p&15) ^ ((L>>2)&7)
#pragma unroll
    for (int i = 0; i < 2; ++i) {
#pragma unroll
        for (int j = 0; j < 4; ++j) {
            int p = (2 * w + i) * 4 + j;
            unsigned prow = (unsigned)p * 2048;
#pragma unroll
            for (int q = 0; q < 4; ++q) {
                int Lc = lane * 4 + q;                 // (Lc>>2)&7 == lane&7
                int P = Lc ^ (p & 15) ^ (lane & 7);
                ushort4 hv;
                hv.x = f32_to_bf16(acc[i][j][4 * q + 0]);
                hv.y = f32_to_bf16(acc[i][j][4 * q + 1]);
                hv.z = f32_to_bf16(acc[i][j][4 * q + 2]);
                hv.w = f32_to_bf16(acc[i][j][4 * q + 3]);
                *(ushort4*)((char*)Gs + prow + (unsigned)P * 16 + kh * 8) = hv;
            }
        }
    }
    __syncthreads();

    // ---------------- Phase B ----------------
    f32x16 oA, oB;
#pragma unroll
    for (int q = 0; q < 16; ++q) { oA[q] = 0.f; oB[q] = 0.f; }

    const int czl = w * 32 + lane;
    const bf16x8* wb = (const bf16x8*)&WT2[(size_t)czl * 1024 + 8 * kh];
    const unsigned prow = (unsigned)lane * 2048;
    const int p15 = lane & 15;

#define LDG(dst, kk) do { \
    int Lr = (kk) * 2 + kh; \
    int P = Lr ^ p15 ^ ((Lr >> 2) & 7); \
    dst = *(const bf16x8*)((const char*)Gs + prow + (unsigned)P * 16); } while (0)

    bf16x8 G0[8], W0[8], G1[8], W1[8];
#define LD8(Gg, Ww, kb) do { \
    LDG(Gg[0], (kb) + 0); LDG(Gg[1], (kb) + 1); LDG(Gg[2], (kb) + 2); LDG(Gg[3], (kb) + 3); \
    LDG(Gg[4], (kb) + 4); LDG(Gg[5], (kb) + 5); LDG(Gg[6], (kb) + 6); LDG(Gg[7], (kb) + 7); \
    Ww[0] = wb[2 * ((kb) + 0)]; Ww[1] = wb[2 * ((kb) + 1)]; \
    Ww[2] = wb[2 * ((kb) + 2)]; Ww[3] = wb[2 * ((kb) + 3)]; \
    Ww[4] = wb[2 * ((kb) + 4)]; Ww[5] = wb[2 * ((kb) + 5)]; \
    Ww[6] = wb[2 * ((kb) + 6)]; Ww[7] = wb[2 * ((kb) + 7)]; } while (0)

#define PH_B(Gg, Ww) do { \
    oA = MFMA(Gg[0], Ww[0], oA, 0, 0, 0); oB = MFMA(Gg[1], Ww[1], oB, 0, 0, 0); \
    oA = MFMA(Gg[2], Ww[2], oA, 0, 0, 0); oB = MFMA(Gg[3], Ww[3], oB, 0, 0, 0); \
    oA = MFMA(Gg[4], Ww[4], oA, 0, 0, 0); oB = MFMA(Gg[5], Ww[5], oB, 0, 0, 0); \
    oA = MFMA(Gg[6], Ww[6], oA, 0, 0, 0); oB = MFMA(Gg[7], Ww[7], oB, 0, 0, 0); } while (0)

    LD8(G0, W0, 0);
#pragma unroll
    for (int kk = 0; kk < 64; kk += 16) {
        LD8(G1, W1, kk + 8);
        PH_B(G0, W0);
        LD8(G0, W0, (kk + 16) & 63);
        PH_B(G1, W1);
    }
    f32x16 o = oA + oB;

#pragma unroll
    for (int reg = 0; reg < 16; ++reg) {
        int p = (reg & 3) + 8 * (reg >> 2) + 4 * kh;
        int pr = p >> 2, pt = p & 3;
        out[((size_t)(r0 + pr) * 256 + (t0 + pt)) * 128 + czl] = o[reg];
    }
}

extern "C" void kernel_launch(void* const* d_in, const int* in_sizes, int n_in,
                              void* d_out, int out_size, void* d_ws, size_t ws_size,
                              hipStream_t stream) {
    const float* msa = (const float*)d_in[0];
    const float* left = (const float*)d_in[1];
    const float* right = (const float*)d_in[2];
    const float* W = (const float*)d_in[3];

    unsigned short* aT = (unsigned short*)d_ws;                 // 2 MB
    unsigned short* bT = aT + (size_t)R * 32 * 128;             // 2 MB
    unsigned short* WT2 = bT + (size_t)R * 32 * 128;            // 256 KB
    unsigned short* WLRT = WT2 + (size_t)128 * 1024;            // 32 KB
    float* outp = (float*)d_out;

    k_wt<<<512, 256, 0, stream>>>(W, WT2);
    k_wlr<<<64, 256, 0, stream>>>(left, right, WLRT);
    k_proj<<<256, 256, 0, stream>>>(msa, WLRT, aT, bT);
    k_main<<<dim3(32, 64), 256, 0, stream>>>(aT, bT, WT2, outp);
}

// Round 3
// 67.005 us; speedup vs baseline: 2.2467x; 1.9226x over previous
//
#include <hip/hip_runtime.h>

typedef __bf16 bf16x8 __attribute__((ext_vector_type(8)));
typedef float f32x16 __attribute__((ext_vector_type(16)));

constexpr int S = 128, R = 256, CM = 256, C = 32, CZ = 128;

#define MFMA __builtin_amdgcn_mfma_f32_32x32x16_bf16

__device__ __forceinline__ unsigned short f32_to_bf16(float f) {
    unsigned int u = __builtin_bit_cast(unsigned int, f);
    u += 0x7FFFu + ((u >> 16) & 1u);
    return (unsigned short)(u >> 16);
}

// K0a: fragment-packed out_proj. k = e*32+c (phase-B K index), frag f = k>>3,
// WTf[f][cz][e0] with e0 = k&7:  WTf[((k>>3)*128 + cz)*8 + (k&7)] = W[(c*32+e)*128+cz]
__global__ __launch_bounds__(256) void k_wt(const float* __restrict__ W,
                                            unsigned short* __restrict__ WTf) {
    int g = blockIdx.x * 256 + threadIdx.x;   // 512 blocks -> 131072 elems
    int cz = g & 127;
    int k = g >> 7;                           // ce' = e*32 + c
    int e = k >> 5, c = k & 31;
    float v = W[(size_t)(c * 32 + e) * 128 + cz];
    WTf[((size_t)(k >> 3) * 128 + cz) * 8 + (k & 7)] = f32_to_bf16(v);
}

// K0b: WLRT[c][m], c in [0,64): c<32 -> left[m][c], else right[m][c-32]
__global__ __launch_bounds__(256) void k_wlr(const float* __restrict__ Lp,
                                             const float* __restrict__ Rp,
                                             unsigned short* __restrict__ WLRT) {
    int c = blockIdx.x;
    int m = threadIdx.x;
    const float* src = (c < 32) ? Lp : Rp;
    WLRT[(size_t)c * 256 + m] = f32_to_bf16(src[(size_t)m * 32 + (c & 31)]);
}

// K1 (MFMA): per block one r. D[s][c] = sum_m msa[s][r][m]*WLR[m][c].
// Writes fragment-packed aTf/bTf[r][ks][khf][c][8s]:
//   elem = r*4096 + ks*512 + khf*256 + c*8 + e0,  s = ks*16 + khf*8 + e0
__global__ __launch_bounds__(256) void k_proj(const float* __restrict__ msa,
                                              const unsigned short* __restrict__ WLRT,
                                              unsigned short* __restrict__ aTf,
                                              unsigned short* __restrict__ bTf) {
    __shared__ __align__(16) unsigned short As[128 * 256];   // 64 KB, swizzled
    const int r = blockIdx.x;
    const int t = threadIdx.x;
    const int w = t >> 6;
    const int lane = t & 63;

#pragma unroll 4
    for (int it = 0; it < 32; ++it) {
        int row = it * 4 + w;
        float4 v = *(const float4*)&msa[((size_t)row * R + r) * CM + lane * 4];
        ushort4 h;
        h.x = f32_to_bf16(v.x); h.y = f32_to_bf16(v.y);
        h.z = f32_to_bf16(v.z); h.w = f32_to_bf16(v.w);
        int P = (lane >> 1) ^ (row & 15);
        *(ushort4*)((char*)As + row * 512 + P * 16 + (lane & 1) * 8) = h;
    }
    __syncthreads();

    const int l31 = t & 31;
    const int kh = (t >> 5) & 1;
    f32x16 accL, accR;
#pragma unroll
    for (int q = 0; q < 16; ++q) { accL[q] = 0.f; accR[q] = 0.f; }

    const bf16x8* wbL = (const bf16x8*)&WLRT[(size_t)l31 * 256 + 8 * kh];
    const bf16x8* wbR = (const bf16x8*)&WLRT[(size_t)(32 + l31) * 256 + 8 * kh];
    const int srow = w * 32 + l31;
    const char* arow = (const char*)As + srow * 512;

    __builtin_amdgcn_s_setprio(1);
#pragma unroll
    for (int ks = 0; ks < 16; ++ks) {
        int P = (2 * ks + kh) ^ (srow & 15);
        bf16x8 af = *(const bf16x8*)(arow + P * 16);
        accL = MFMA(af, wbL[2 * ks], accL, 0, 0, 0);
        accR = MFMA(af, wbR[2 * ks], accR, 0, 0, 0);
    }
    __builtin_amdgcn_s_setprio(0);

    // D: col=l31 (c), row -> s = w*32 + 8q + 4kh + j  (j = reg&3, q = reg>>2)
    // ks = 2w + (q>>1), khf = q&1, e0 = 4kh + j
#pragma unroll
    for (int q = 0; q < 4; ++q) {
        size_t base = (size_t)r * 4096 + (size_t)(2 * w + (q >> 1)) * 512 +
                      (size_t)(q & 1) * 256 + (size_t)l31 * 8 + 4 * kh;
        ushort4 ha, hb;
        ha.x = f32_to_bf16(accL[4 * q + 0]); ha.y = f32_to_bf16(accL[4 * q + 1]);
        ha.z = f32_to_bf16(accL[4 * q + 2]); ha.w = f32_to_bf16(accL[4 * q + 3]);
        hb.x = f32_to_bf16(accR[4 * q + 0]); hb.y = f32_to_bf16(accR[4 * q + 1]);
        hb.z = f32_to_bf16(accR[4 * q + 2]); hb.w = f32_to_bf16(accR[4 * q + 3]);
        *(ushort4*)&aTf[base] = ha;
        *(ushort4*)&bTf[base] = hb;
    }
}

// K2: 32 pairs (8r x 4t) per block, 4 waves. All global operand loads are
// wave-contiguous (fragment-packed). G through swizzled LDS.
__global__ __launch_bounds__(256, 2) void k_main(const unsigned short* __restrict__ aTf,
                                                 const unsigned short* __restrict__ bTf,
                                                 const unsigned short* __restrict__ WTf,
                                                 float* __restrict__ out) {
    __shared__ __align__(16) unsigned short Gs[32 * 1024];   // 64 KB

    const int t = threadIdx.x;
    const int w = t >> 6;
    const int l = t & 63;
    const int lane = l & 31;
    const int kh = l >> 5;
    const int r0 = blockIdx.x * 8;
    const int t0 = blockIdx.y * 4;

    // ---------------- Phase A ----------------
    f32x16 acc[2][4];
#pragma unroll
    for (int i = 0; i < 2; ++i)
#pragma unroll
        for (int j = 0; j < 4; ++j)
#pragma unroll
            for (int q = 0; q < 16; ++q) acc[i][j][q] = 0.f;

    // frag(row, ks) at base[ks*64] (bf16x8 units), base folds kh,lane
    const bf16x8* ap0 = (const bf16x8*)aTf + ((size_t)(r0 + 2 * w + 0) * 512 + kh * 32 + lane);
    const bf16x8* ap1 = (const bf16x8*)aTf + ((size_t)(r0 + 2 * w + 1) * 512 + kh * 32 + lane);
    const bf16x8* bp0 = (const bf16x8*)bTf + ((size_t)(t0 + 0) * 512 + kh * 32 + lane);
    const bf16x8* bp1 = (const bf16x8*)bTf + ((size_t)(t0 + 1) * 512 + kh * 32 + lane);
    const bf16x8* bp2 = (const bf16x8*)bTf + ((size_t)(t0 + 2) * 512 + kh * 32 + lane);
    const bf16x8* bp3 = (const bf16x8*)bTf + ((size_t)(t0 + 3) * 512 + kh * 32 + lane);

    bf16x8 A0[2], B0[4], A1[2], B1[4];
#define LDA(Aa, Bb, ks) do { \
    Aa[0] = ap0[(ks) * 64]; Aa[1] = ap1[(ks) * 64]; \
    Bb[0] = bp0[(ks) * 64]; Bb[1] = bp1[(ks) * 64]; \
    Bb[2] = bp2[(ks) * 64]; Bb[3] = bp3[(ks) * 64]; } while (0)
#define PH_A(Aa, Bb) do { \
    __builtin_amdgcn_s_setprio(1); \
    acc[0][0] = MFMA(Aa[0], Bb[0], acc[0][0], 0, 0, 0); \
    acc[0][1] = MFMA(Aa[0], Bb[1], acc[0][1], 0, 0, 0); \
    acc[0][2] = MFMA(Aa[0], Bb[2], acc[0][2], 0, 0, 0); \
    acc[0][3] = MFMA(Aa[0], Bb[3], acc[0][3], 0, 0, 0); \
    acc[1][0] = MFMA(Aa[1], Bb[0], acc[1][0], 0, 0, 0); \
    acc[1][1] = MFMA(Aa[1], Bb[1], acc[1][1], 0, 0, 0); \
    acc[1][2] = MFMA(Aa[1], Bb[2], acc[1][2], 0, 0, 0); \
    acc[1][3] = MFMA(Aa[1], Bb[3], acc[1][3], 0, 0, 0); \
    __builtin_amdgcn_s_setprio(0); } while (0)

    LDA(A0, B0, 0);
#pragma unroll
    for (int ks = 0; ks < 8; ks += 2) {
        LDA(A1, B1, ks + 1);
        PH_A(A0, B0);
        LDA(A0, B0, (ks + 2) & 7);
        PH_A(A1, B1);
    }

    // G -> LDS bf16, row p (2048 B), chunk swizzle P = L ^ (p&15) ^ ((L>>2)&7)
#pragma unroll
    for (int i = 0; i < 2; ++i) {
#pragma unroll
        for (int j = 0; j < 4; ++j) {
            int p = (2 * w + i) * 4 + j;
            unsigned prow = (unsigned)p * 2048;
#pragma unroll
            for (int q = 0; q < 4; ++q) {
                int Lc = lane * 4 + q;
                int P = Lc ^ (p & 15) ^ (lane & 7);
                ushort4 hv;
                hv.x = f32_to_bf16(acc[i][j][4 * q + 0]);
                hv.y = f32_to_bf16(acc[i][j][4 * q + 1]);
                hv.z = f32_to_bf16(acc[i][j][4 * q + 2]);
                hv.w = f32_to_bf16(acc[i][j][4 * q + 3]);
                *(ushort4*)((char*)Gs + prow + (unsigned)P * 16 + kh * 8) = hv;
            }
        }
    }
    __syncthreads();

    // ---------------- Phase B ----------------
    f32x16 oA, oB;
#pragma unroll
    for (int q = 0; q < 16; ++q) { oA[q] = 0.f; oB[q] = 0.f; }

    const int czl = w * 32 + lane;
    // W frag(kk) at wb[kk*256] (bf16x8 units)
    const bf16x8* wb = (const bf16x8*)WTf + ((size_t)kh * 128 + czl);
    const unsigned prow = (unsigned)lane * 2048;
    const int p15 = lane & 15;

#define LDG(dst, kk) do { \
    int Lr = (kk) * 2 + kh; \
    int P = Lr ^ p15 ^ ((Lr >> 2) & 7); \
    dst = *(const bf16x8*)((const char*)Gs + prow + (unsigned)P * 16); } while (0)

    bf16x8 G0[8], W0[8], G1[8], W1[8];
#define LD8(Gg, Ww, kb) do { \
    LDG(Gg[0], (kb) + 0); LDG(Gg[1], (kb) + 1); LDG(Gg[2], (kb) + 2); LDG(Gg[3], (kb) + 3); \
    LDG(Gg[4], (kb) + 4); LDG(Gg[5], (kb) + 5); LDG(Gg[6], (kb) + 6); LDG(Gg[7], (kb) + 7); \
    Ww[0] = wb[((kb) + 0) * 256]; Ww[1] = wb[((kb) + 1) * 256]; \
    Ww[2] = wb[((kb) + 2) * 256]; Ww[3] = wb[((kb) + 3) * 256]; \
    Ww[4] = wb[((kb) + 4) * 256]; Ww[5] = wb[((kb) + 5) * 256]; \
    Ww[6] = wb[((kb) + 6) * 256]; Ww[7] = wb[((kb) + 7) * 256]; } while (0)

#define PH_B(Gg, Ww) do { \
    __builtin_amdgcn_s_setprio(1); \
    oA = MFMA(Gg[0], Ww[0], oA, 0, 0, 0); oB = MFMA(Gg[1], Ww[1], oB, 0, 0, 0); \
    oA = MFMA(Gg[2], Ww[2], oA, 0, 0, 0); oB = MFMA(Gg[3], Ww[3], oB, 0, 0, 0); \
    oA = MFMA(Gg[4], Ww[4], oA, 0, 0, 0); oB = MFMA(Gg[5], Ww[5], oB, 0, 0, 0); \
    oA = MFMA(Gg[6], Ww[6], oA, 0, 0, 0); oB = MFMA(Gg[7], Ww[7], oB, 0, 0, 0); \
    __builtin_amdgcn_s_setprio(0); } while (0)

    LD8(G0, W0, 0);
#pragma unroll
    for (int kk = 0; kk < 64; kk += 16) {
        LD8(G1, W1, kk + 8);
        PH_B(G0, W0);
        LD8(G0, W0, (kk + 16) & 63);
        PH_B(G1, W1);
    }
    f32x16 o = oA + oB;

#pragma unroll
    for (int reg = 0; reg < 16; ++reg) {
        int p = (reg & 3) + 8 * (reg >> 2) + 4 * kh;
        int pr = p >> 2, pt = p & 3;
        out[((size_t)(r0 + pr) * 256 + (t0 + pt)) * 128 + czl] = o[reg];
    }
}

extern "C" void kernel_launch(void* const* d_in, const int* in_sizes, int n_in,
                              void* d_out, int out_size, void* d_ws, size_t ws_size,
                              hipStream_t stream) {
    const float* msa = (const float*)d_in[0];
    const float* left = (const float*)d_in[1];
    const float* right = (const float*)d_in[2];
    const float* W = (const float*)d_in[3];

    unsigned short* aTf = (unsigned short*)d_ws;                // 2 MB
    unsigned short* bTf = aTf + (size_t)R * 4096;               // 2 MB
    unsigned short* WTf = bTf + (size_t)R * 4096;               // 256 KB
    unsigned short* WLRT = WTf + (size_t)128 * 1024;            // 32 KB
    float* outp = (float*)d_out;

    k_wt<<<512, 256, 0, stream>>>(W, WTf);
    k_wlr<<<64, 256, 0, stream>>>(left, right, WLRT);
    k_proj<<<256, 256, 0, stream>>>(msa, WLRT, aTf, bTf);
    k_main<<<dim3(32, 64), 256, 0, stream>>>(aTf, bTf, WTf, outp);
}